// Round 1
// baseline (1345.987 us; speedup 1.0000x reference)
//
#include <hip/hip_runtime.h>
#include <math.h>

// Shapes (fixed by setup_inputs): B=8, n=32, C=64, O=64
#define NB 8
#define NN 32
#define NC 64
#define NO 64

// ---- workspace layout (float offsets). Total 1,261,568 floats = ~4.82 MB ----
#define WS_G    0         // 4 floats: gate for o0..o3 (any over all b of bit-range)
#define WS_MF   16        // 80 floats: act as float, [b*10+bit]
#define WS_R1   128       // B*2C   = 1024   : reduce(x1,1)  interleaved (max,min)
#define WS_R2   2048      // B*N*2C = 32768  : reduce(x2,2)
#define WS_R3   65536     // B*N*N*2C = 1048576 : reduce(x3,3)
#define WS_WTE2 1179648   // 128*64 : w_exp2 transposed [c*64+o]
#define WS_WTO2 1187840   // 128*64 : w_op2^T
#define WS_WTR2 1196032   // 256*64 : w_red2^T
#define WS_WTE3 1212416   // 384*64 : w_exp3^T
#define WS_WTO3 1236992   // 384*64 : w_op3^T
// end = 1261568 floats

__device__ __forceinline__ float sigmoidf_(float s) {
    return 1.0f / (1.0f + expf(-s));
}

// ---- prep: gates + per-b float masks ----
__global__ void prep_gm(const int* __restrict__ act, float* __restrict__ ws) {
    int t = threadIdx.x;
    if (t < 80) ws[WS_MF + t] = (act[t] == 1) ? 1.0f : 0.0f;
    if (t < 4) {
        const int lo[4] = {0, 2, 5, 8};
        const int hi[4] = {2, 5, 8, 10};
        int any = 0;
        for (int b = 0; b < NB; ++b)
            for (int bit = lo[t]; bit < hi[t]; ++bit)
                any |= (act[b * 10 + bit] == 1);
        ws[WS_G + t] = any ? 1.0f : 0.0f;
    }
}

// ---- prep: transpose the o2/o3 weight matrices so lane=o reads coalesce ----
__global__ void prep_wt(const float* __restrict__ we2, const float* __restrict__ wo2,
                        const float* __restrict__ wr2, const float* __restrict__ we3,
                        const float* __restrict__ wo3, float* __restrict__ ws) {
    int tid = blockIdx.x * blockDim.x + threadIdx.x;
    if (tid >= 81920) return;
    const float* src; float* dst; int K; int local;
    if (tid < 8192)       { src = we2; dst = ws + WS_WTE2; K = 128; local = tid; }
    else if (tid < 16384) { src = wo2; dst = ws + WS_WTO2; K = 128; local = tid - 8192; }
    else if (tid < 32768) { src = wr2; dst = ws + WS_WTR2; K = 256; local = tid - 16384; }
    else if (tid < 57344) { src = we3; dst = ws + WS_WTE3; K = 384; local = tid - 32768; }
    else                  { src = wo3; dst = ws + WS_WTO3; K = 384; local = tid - 57344; }
    int cc = local >> 6, oo = local & 63;
    dst[local] = src[oo * K + cc];    // dst[c*64+o] = w[o,c]
}

// ---- reduce(x1, 1): no mask. out interleaved [2c]=max, [2c+1]=min ----
__global__ __launch_bounds__(64) void red1(const float* __restrict__ x1, float* __restrict__ ws) {
    int b = blockIdx.x, c = threadIdx.x;
    float mx = -INFINITY, mn = INFINITY;
    for (int k = 0; k < NN; ++k) {
        float v = x1[(b * NN + k) * NC + c];
        mx = fmaxf(mx, v); mn = fminf(mn, v);
    }
    ws[WS_R1 + b * 2 * NC + 2 * c]     = mx;
    ws[WS_R1 + b * 2 * NC + 2 * c + 1] = mn;
}

// ---- reduce(x2, 2): diagonal j==i masked (0 for max, 1 for min) ----
__global__ __launch_bounds__(64) void red2(const float* __restrict__ x2, float* __restrict__ ws) {
    int blk = blockIdx.x; int i = blk % NN, b = blk / NN; int c = threadIdx.x;
    float mx = -INFINITY, mn = INFINITY;
    for (int jj = 0; jj < NN; ++jj) {
        float v = x2[((b * NN + i) * NN + jj) * NC + c];
        mx = fmaxf(mx, (jj == i) ? 0.0f : v);
        mn = fminf(mn, (jj == i) ? 1.0f : v);
    }
    ws[WS_R2 + (b * NN + i) * 2 * NC + 2 * c]     = mx;
    ws[WS_R2 + (b * NN + i) * 2 * NC + 2 * c + 1] = mn;
}

// ---- reduce(x3, 3): entries with any repeated index among (i,j,k) masked ----
__global__ __launch_bounds__(64) void red3(const float* __restrict__ x3, float* __restrict__ ws) {
    int blk = blockIdx.x;
    int j = blk % NN, i = (blk / NN) % NN, b = blk / (NN * NN);
    int c = threadIdx.x;
    float mx = -INFINITY, mn = INFINITY;
    for (int k = 0; k < NN; ++k) {
        float v = x3[(((b * NN + i) * NN + j) * NN + k) * NC + c];
        bool bad = (i == j) || (k == i) || (k == j);
        mx = fmaxf(mx, bad ? 0.0f : v);
        mn = fminf(mn, bad ? 1.0f : v);
    }
    ws[WS_R3 + ((b * NN + i) * NN + j) * 2 * NC + 2 * c]     = mx;
    ws[WS_R3 + ((b * NN + i) * NN + j) * 2 * NC + 2 * c + 1] = mn;
}

// ---- o0: [B, O] ----
__global__ __launch_bounds__(64) void out0k(
        const float* __restrict__ x0,
        const float* __restrict__ w_op0, const float* __restrict__ b_op0,
        const float* __restrict__ w_red0, const float* __restrict__ b_red0,
        const float* __restrict__ ws, float* __restrict__ out) {
    int b = blockIdx.x, o = threadIdx.x;
    float g  = ws[WS_G + 0];
    float m0 = ws[WS_MF + b * 10 + 0], m1 = ws[WS_MF + b * 10 + 1];
    float d0 = b_op0[o];
    for (int c = 0; c < NC; ++c) d0 += w_op0[o * NC + c] * x0[b * NC + c];
    float d1 = b_red0[o];
    for (int c = 0; c < 2 * NC; ++c) d1 += w_red0[o * 2 * NC + c] * ws[WS_R1 + b * 2 * NC + c];
    float s = m0 * d0 + m1 * d1;
    out[b * NO + o] = (g != 0.0f) ? sigmoidf_(s) : 0.0f;
}

// ---- o1: [B, n, O] ----
__global__ __launch_bounds__(64) void out1k(
        const float* __restrict__ x0, const float* __restrict__ x1,
        const float* __restrict__ w_e1, const float* __restrict__ b_e1,
        const float* __restrict__ w_o1, const float* __restrict__ b_o1,
        const float* __restrict__ w_r1, const float* __restrict__ b_r1,
        const float* __restrict__ ws, float* __restrict__ out) {
    int blk = blockIdx.x; int i = blk % NN, b = blk / NN; int o = threadIdx.x;
    float g  = ws[WS_G + 1];
    float m2 = ws[WS_MF + b * 10 + 2];
    float m3 = ws[WS_MF + b * 10 + 3];
    float m4 = ws[WS_MF + b * 10 + 4];
    float d2 = b_e1[o];
    for (int c = 0; c < NC; ++c) d2 += w_e1[o * NC + c] * x0[b * NC + c];
    float d3 = b_o1[o];
    for (int c = 0; c < NC; ++c) d3 += w_o1[o * NC + c] * x1[(b * NN + i) * NC + c];
    float d4 = b_r1[o];
    for (int c = 0; c < 2 * NC; ++c) d4 += w_r1[o * 2 * NC + c] * ws[WS_R2 + (b * NN + i) * 2 * NC + c];
    float s = m2 * d2 + m3 * d3 + m4 * d4;
    out[(b * NN + i) * NO + o] = (g != 0.0f) ? sigmoidf_(s) : 0.0f;
}

// ---- o2: [B, n, n, O], one wave per (b,i,j) ----
__global__ __launch_bounds__(64) void out2k(
        const float* __restrict__ x1, const float* __restrict__ x2,
        const float* __restrict__ b_e2, const float* __restrict__ b_o2,
        const float* __restrict__ b_r2,
        const float* __restrict__ ws, float* __restrict__ out) {
    __shared__ float fe[128], fo[128], fr[256];
    int blk = blockIdx.x;
    int j = blk % NN, i = (blk / NN) % NN, b = blk / (NN * NN);
    int o = threadIdx.x;
    float g  = ws[WS_G + 2];
    float m5 = ws[WS_MF + b * 10 + 5];
    float m6 = ws[WS_MF + b * 10 + 6];
    float m7 = ws[WS_MF + b * 10 + 7];
    // features: exp2 = [x1[b,i],x1[b,j]]; op2 = [x2[b,i,j],x2[b,j,i]]; red2 = [r3[b,i,j],r3[b,j,i]]
    fe[o]       = x1[(b * NN + i) * NC + o];
    fe[o + 64]  = x1[(b * NN + j) * NC + o];
    fo[o]       = x2[((b * NN + i) * NN + j) * NC + o];
    fo[o + 64]  = x2[((b * NN + j) * NN + i) * NC + o];
    const float* r3ij = ws + WS_R3 + ((b * NN + i) * NN + j) * 128;
    const float* r3ji = ws + WS_R3 + ((b * NN + j) * NN + i) * 128;
    fr[o]        = r3ij[o];
    fr[o + 64]   = r3ij[o + 64];
    fr[o + 128]  = r3ji[o];
    fr[o + 192]  = r3ji[o + 64];
    __syncthreads();
    const float* wte2 = ws + WS_WTE2;
    const float* wto2 = ws + WS_WTO2;
    const float* wtr2 = ws + WS_WTR2;
    float d5 = 0.0f, d6 = 0.0f, d7 = 0.0f;
    #pragma unroll 4
    for (int c = 0; c < 128; ++c) {
        d5 += wte2[c * 64 + o] * fe[c];
        d6 += wto2[c * 64 + o] * fo[c];
    }
    #pragma unroll 4
    for (int c = 0; c < 256; ++c) d7 += wtr2[c * 64 + o] * fr[c];
    float s = m5 * (b_e2[o] + d5) + m6 * (b_o2[o] + d6) + m7 * (b_r2[o] + d7);
    out[((b * NN + i) * NN + j) * NO + o] = (g != 0.0f) ? sigmoidf_(s) : 0.0f;
}

// ---- o3: [B, n, n, n, O], block per (b,i,j), 2 phases of 16 k each ----
// op3 chunk order (w_op3 col blocks): x3 at (i,j,k),(i,k,j),(j,i,k),(k,i,j),(j,k,i),(k,j,i)
// exp3 chunk order (w_exp3 col blocks): x2 at (i,j),(i,k),(j,i),(k,i),(j,k),(k,j)
__global__ __launch_bounds__(256) void out3k(
        const float* __restrict__ x2, const float* __restrict__ x3,
        const float* __restrict__ b_e3, const float* __restrict__ b_o3,
        const float* __restrict__ ws, float* __restrict__ out) {
    __shared__ float xp[6][16][64];   // 6 permuted x3 planes (k-half x C)
    __shared__ float pq[4][16][64];   // k-dependent x2 planes: (i,k),(k,i),(j,k),(k,j)
    __shared__ float xq1[64], xq3[64];// k-independent x2 rows: (i,j),(j,i)
    int blk = blockIdx.x;
    int j = blk & 31, i = (blk >> 5) & 31, b = blk >> 10;
    int t = threadIdx.x;
    int o = t & 63, wq = t >> 6;      // lane = output o, wave = k-quad
    float g3 = ws[WS_G + 3];
    float m8 = ws[WS_MF + b * 10 + 8], m9 = ws[WS_MF + b * 10 + 9];
    const float* wte3 = ws + WS_WTE3;
    const float* wto3 = ws + WS_WTO3;
    if (t < 64)        xq1[t]      = x2[((b * NN + i) * NN + j) * NC + t];
    else if (t < 128)  xq3[t - 64] = x2[((b * NN + j) * NN + i) * NC + (t - 64)];
    __syncthreads();
    // k-independent exp3 partial: chunks 0 (x2[i,j]) and 2 (x2[j,i])
    float sbe = 0.0f;
    #pragma unroll 4
    for (int c = 0; c < NC; ++c) {
        sbe += wte3[(0 * 64 + c) * 64 + o] * xq1[c];
        sbe += wte3[(2 * 64 + c) * 64 + o] * xq3[c];
    }
    float be = b_e3[o], bo = b_o3[o];
    int cst = t & 63, rr = t >> 6;
    for (int h = 0; h < 2; ++h) {
        __syncthreads();   // previous phase's compute done before restaging
        #pragma unroll
        for (int s4 = 0; s4 < 4; ++s4) {
            int kk = s4 * 4 + rr, k = h * 16 + kk;
            xp[0][kk][cst] = x3[(((b * NN + i) * NN + j) * NN + k) * NC + cst];
            xp[1][kk][cst] = x3[(((b * NN + i) * NN + k) * NN + j) * NC + cst];
            xp[2][kk][cst] = x3[(((b * NN + j) * NN + i) * NN + k) * NC + cst];
            xp[3][kk][cst] = x3[(((b * NN + k) * NN + i) * NN + j) * NC + cst];
            xp[4][kk][cst] = x3[(((b * NN + j) * NN + k) * NN + i) * NC + cst];
            xp[5][kk][cst] = x3[(((b * NN + k) * NN + j) * NN + i) * NC + cst];
            pq[0][kk][cst] = x2[((b * NN + i) * NN + k) * NC + cst];
            pq[1][kk][cst] = x2[((b * NN + k) * NN + i) * NC + cst];
            pq[2][kk][cst] = x2[((b * NN + j) * NN + k) * NC + cst];
            pq[3][kk][cst] = x2[((b * NN + k) * NN + j) * NC + cst];
        }
        __syncthreads();
        float ao0 = 0.f, ao1 = 0.f, ao2 = 0.f, ao3 = 0.f;  // op3 accumulators (4 k's)
        float ae0 = 0.f, ae1 = 0.f, ae2 = 0.f, ae3 = 0.f;  // exp3 (k-dep) accumulators
        int k0 = wq * 4;
        #pragma unroll 4
        for (int cc = 0; cc < NC; ++cc) {
            #pragma unroll
            for (int m = 0; m < 6; ++m) {
                float w = wto3[(m * 64 + cc) * 64 + o];
                ao0 += w * xp[m][k0 + 0][cc];
                ao1 += w * xp[m][k0 + 1][cc];
                ao2 += w * xp[m][k0 + 2][cc];
                ao3 += w * xp[m][k0 + 3][cc];
            }
            float w1 = wte3[(1 * 64 + cc) * 64 + o];
            float w3 = wte3[(3 * 64 + cc) * 64 + o];
            float w4 = wte3[(4 * 64 + cc) * 64 + o];
            float w5 = wte3[(5 * 64 + cc) * 64 + o];
            ae0 += w1 * pq[0][k0 + 0][cc] + w3 * pq[1][k0 + 0][cc] + w4 * pq[2][k0 + 0][cc] + w5 * pq[3][k0 + 0][cc];
            ae1 += w1 * pq[0][k0 + 1][cc] + w3 * pq[1][k0 + 1][cc] + w4 * pq[2][k0 + 1][cc] + w5 * pq[3][k0 + 1][cc];
            ae2 += w1 * pq[0][k0 + 2][cc] + w3 * pq[1][k0 + 2][cc] + w4 * pq[2][k0 + 2][cc] + w5 * pq[3][k0 + 2][cc];
            ae3 += w1 * pq[0][k0 + 3][cc] + w3 * pq[1][k0 + 3][cc] + w4 * pq[2][k0 + 3][cc] + w5 * pq[3][k0 + 3][cc];
        }
        int obase = ((b * NN + i) * NN + j) * NN + h * 16 + k0;
        float s0 = m8 * (be + sbe + ae0) + m9 * (bo + ao0);
        float s1 = m8 * (be + sbe + ae1) + m9 * (bo + ao1);
        float s2 = m8 * (be + sbe + ae2) + m9 * (bo + ao2);
        float s3 = m8 * (be + sbe + ae3) + m9 * (bo + ao3);
        out[(obase + 0) * NO + o] = (g3 != 0.0f) ? sigmoidf_(s0) : 0.0f;
        out[(obase + 1) * NO + o] = (g3 != 0.0f) ? sigmoidf_(s1) : 0.0f;
        out[(obase + 2) * NO + o] = (g3 != 0.0f) ? sigmoidf_(s2) : 0.0f;
        out[(obase + 3) * NO + o] = (g3 != 0.0f) ? sigmoidf_(s3) : 0.0f;
    }
}

extern "C" void kernel_launch(void* const* d_in, const int* in_sizes, int n_in,
                              void* d_out, int out_size, void* d_ws, size_t ws_size,
                              hipStream_t stream) {
    const float* x0 = (const float*)d_in[0];
    const float* x1 = (const float*)d_in[1];
    const float* x2 = (const float*)d_in[2];
    const float* x3 = (const float*)d_in[3];
    const float* w_op0 = (const float*)d_in[4];   const float* b_op0 = (const float*)d_in[5];
    const float* w_red0 = (const float*)d_in[6];  const float* b_red0 = (const float*)d_in[7];
    const float* w_exp1 = (const float*)d_in[8];  const float* b_exp1 = (const float*)d_in[9];
    const float* w_op1 = (const float*)d_in[10];  const float* b_op1 = (const float*)d_in[11];
    const float* w_red1 = (const float*)d_in[12]; const float* b_red1 = (const float*)d_in[13];
    const float* w_exp2 = (const float*)d_in[14]; const float* b_exp2 = (const float*)d_in[15];
    const float* w_op2 = (const float*)d_in[16];  const float* b_op2 = (const float*)d_in[17];
    const float* w_red2 = (const float*)d_in[18]; const float* b_red2 = (const float*)d_in[19];
    const float* w_exp3 = (const float*)d_in[20]; const float* b_exp3 = (const float*)d_in[21];
    const float* w_op3 = (const float*)d_in[22];  const float* b_op3 = (const float*)d_in[23];
    const int* act = (const int*)d_in[24];

    float* ws = (float*)d_ws;   // needs ~4.82 MB
    float* out = (float*)d_out;
    float* out0 = out;               // [0, 512)
    float* out1 = out + 512;         // [512, 16896)
    float* out2 = out + 16896;       // [16896, 541184)
    float* out3 = out + 541184;      // [541184, 17318400)

    prep_gm<<<1, 128, 0, stream>>>(act, ws);
    prep_wt<<<320, 256, 0, stream>>>(w_exp2, w_op2, w_red2, w_exp3, w_op3, ws);
    red1<<<NB, 64, 0, stream>>>(x1, ws);
    red2<<<NB * NN, 64, 0, stream>>>(x2, ws);
    red3<<<NB * NN * NN, 64, 0, stream>>>(x3, ws);
    out0k<<<NB, 64, 0, stream>>>(x0, w_op0, b_op0, w_red0, b_red0, ws, out0);
    out1k<<<NB * NN, 64, 0, stream>>>(x0, x1, w_exp1, b_exp1, w_op1, b_op1, w_red1, b_red1, ws, out1);
    out2k<<<NB * NN * NN, 64, 0, stream>>>(x1, x2, b_exp2, b_op2, b_red2, ws, out2);
    out3k<<<NB * NN * NN, 256, 0, stream>>>(x2, x3, b_exp3, b_op3, ws, out3);
}

// Round 2
// 327.472 us; speedup vs baseline: 4.1102x; 4.1102x over previous
//
#include <hip/hip_runtime.h>
#include <math.h>

// Shapes (fixed by setup_inputs): B=8, n=32, C=64, O=64
#define NB 8
#define NN 32
#define NC 64
#define NO 64

// ---- workspace layout (float offsets) ----
#define WS_G    0         // 4 floats: gate for o0..o3
#define WS_MF   16        // 80 floats: act as float
#define WS_R1   128       // B*2C
#define WS_R2   2048      // B*N*2C
#define WS_R3   65536     // B*N*N*2C
#define WS_WTE2 1179648   // 128*64 : w_exp2^T
#define WS_WTO2 1187840   // 128*64 : w_op2^T
#define WS_WTR2 1196032   // 256*64 : w_red2^T
#define WS_BB   1261568   // 512 floats: per-b combined o3 bias (m8*b_e3 + m9*b_o3)
#define WS_WC   1262080   // 393216 ushorts (196608 floats): per-b combined o3 weights,
                          // bf16, fragment-ordered [b][nt][kk][lane][8]
// end = 1458688 floats (~5.84 MB)

typedef short bf16x8 __attribute__((ext_vector_type(8)));
typedef float f32x4 __attribute__((ext_vector_type(4)));

__device__ __forceinline__ float sigmoidf_(float s) {
    return 1.0f / (1.0f + expf(-s));
}

__device__ __forceinline__ unsigned short f2bf(float x) {
    union { float f; unsigned int u; } v; v.f = x;
    unsigned int u = v.u;
    u += 0x7FFFu + ((u >> 16) & 1u);   // round-to-nearest-even
    return (unsigned short)(u >> 16);
}

// ---- prep: gates + per-b float masks + o3 combined bias ----
__global__ void prep_gm(const int* __restrict__ act,
                        const float* __restrict__ be3, const float* __restrict__ bo3,
                        float* __restrict__ ws) {
    int t = threadIdx.x;
    if (t < 80) ws[WS_MF + t] = (act[t] == 1) ? 1.0f : 0.0f;
    if (t < 4) {
        const int lo[4] = {0, 2, 5, 8};
        const int hi[4] = {2, 5, 8, 10};
        int any = 0;
        for (int b = 0; b < NB; ++b)
            for (int bit = lo[t]; bit < hi[t]; ++bit)
                any |= (act[b * 10 + bit] == 1);
        ws[WS_G + t] = any ? 1.0f : 0.0f;
    }
    if (t < 512) {
        int b = t >> 6, o = t & 63;
        float m8 = (act[b * 10 + 8] == 1) ? 1.0f : 0.0f;
        float m9 = (act[b * 10 + 9] == 1) ? 1.0f : 0.0f;
        ws[WS_BB + t] = m8 * be3[o] + m9 * bo3[o];
    }
}

// ---- prep: transpose o2 weights ----
__global__ void prep_wt(const float* __restrict__ we2, const float* __restrict__ wo2,
                        const float* __restrict__ wr2, float* __restrict__ ws) {
    int tid = blockIdx.x * blockDim.x + threadIdx.x;
    if (tid >= 32768) return;
    const float* src; float* dst; int K; int local;
    if (tid < 8192)       { src = we2; dst = ws + WS_WTE2; K = 128; local = tid; }
    else if (tid < 16384) { src = wo2; dst = ws + WS_WTO2; K = 128; local = tid - 8192; }
    else                  { src = wr2; dst = ws + WS_WTR2; K = 256; local = tid - 16384; }
    int cc = local >> 6, oo = local & 63;
    dst[local] = src[oo * K + cc];
}

// ---- prep: per-b combined o3 weight matrix, bf16, MFMA-fragment-ordered ----
// Wc flat index = (((b*4 + nt)*24 + kk)*64 + lane)*8 + i8
// element = (kloc<384 ? m8*w_exp3[o][kloc] : m9*w_op3[o][kloc-384])
// with o = nt*16 + (lane&15), kloc = kk*32 + (lane>>4)*8 + i8
__global__ void prep_wc(const float* __restrict__ we3, const float* __restrict__ wo3,
                        const int* __restrict__ act, float* __restrict__ ws) {
    int tid = blockIdx.x * 256 + threadIdx.x;   // < 393216
    unsigned short* wc = (unsigned short*)(ws + WS_WC);
    int i8 = tid & 7;
    int lane = (tid >> 3) & 63;
    int rest = tid >> 9;          // 0..767 = (b*4+nt)*24 + kk
    int kk = rest % 24;
    int ntb = rest / 24;          // b*4+nt
    int nt = ntb & 3, b = ntb >> 2;
    int o = nt * 16 + (lane & 15);
    int kloc = kk * 32 + ((lane >> 4) << 3) + i8;
    bool m8 = act[b * 10 + 8] == 1;
    bool m9 = act[b * 10 + 9] == 1;
    float val;
    if (kloc < 384) val = m8 ? we3[o * 384 + kloc] : 0.0f;
    else            val = m9 ? wo3[o * 384 + kloc - 384] : 0.0f;
    wc[tid] = f2bf(val);
}

// ---- reduce(x1, 1) ----
__global__ __launch_bounds__(64) void red1(const float* __restrict__ x1, float* __restrict__ ws) {
    int b = blockIdx.x, c = threadIdx.x;
    float mx = -INFINITY, mn = INFINITY;
    for (int k = 0; k < NN; ++k) {
        float v = x1[(b * NN + k) * NC + c];
        mx = fmaxf(mx, v); mn = fminf(mn, v);
    }
    ws[WS_R1 + b * 2 * NC + 2 * c]     = mx;
    ws[WS_R1 + b * 2 * NC + 2 * c + 1] = mn;
}

// ---- reduce(x2, 2) ----
__global__ __launch_bounds__(64) void red2(const float* __restrict__ x2, float* __restrict__ ws) {
    int blk = blockIdx.x; int i = blk % NN, b = blk / NN; int c = threadIdx.x;
    float mx = -INFINITY, mn = INFINITY;
    for (int jj = 0; jj < NN; ++jj) {
        float v = x2[((b * NN + i) * NN + jj) * NC + c];
        mx = fmaxf(mx, (jj == i) ? 0.0f : v);
        mn = fminf(mn, (jj == i) ? 1.0f : v);
    }
    ws[WS_R2 + (b * NN + i) * 2 * NC + 2 * c]     = mx;
    ws[WS_R2 + (b * NN + i) * 2 * NC + 2 * c + 1] = mn;
}

// ---- reduce(x3, 3) ----
__global__ __launch_bounds__(64) void red3(const float* __restrict__ x3, float* __restrict__ ws) {
    int blk = blockIdx.x;
    int j = blk % NN, i = (blk / NN) % NN, b = blk / (NN * NN);
    int c = threadIdx.x;
    float mx = -INFINITY, mn = INFINITY;
    for (int k = 0; k < NN; ++k) {
        float v = x3[(((b * NN + i) * NN + j) * NN + k) * NC + c];
        bool bad = (i == j) || (k == i) || (k == j);
        mx = fmaxf(mx, bad ? 0.0f : v);
        mn = fminf(mn, bad ? 1.0f : v);
    }
    ws[WS_R3 + ((b * NN + i) * NN + j) * 2 * NC + 2 * c]     = mx;
    ws[WS_R3 + ((b * NN + i) * NN + j) * 2 * NC + 2 * c + 1] = mn;
}

// ---- o0 ----
__global__ __launch_bounds__(64) void out0k(
        const float* __restrict__ x0,
        const float* __restrict__ w_op0, const float* __restrict__ b_op0,
        const float* __restrict__ w_red0, const float* __restrict__ b_red0,
        const float* __restrict__ ws, float* __restrict__ out) {
    int b = blockIdx.x, o = threadIdx.x;
    float g  = ws[WS_G + 0];
    float m0 = ws[WS_MF + b * 10 + 0], m1 = ws[WS_MF + b * 10 + 1];
    float d0 = b_op0[o];
    for (int c = 0; c < NC; ++c) d0 += w_op0[o * NC + c] * x0[b * NC + c];
    float d1 = b_red0[o];
    for (int c = 0; c < 2 * NC; ++c) d1 += w_red0[o * 2 * NC + c] * ws[WS_R1 + b * 2 * NC + c];
    float s = m0 * d0 + m1 * d1;
    out[b * NO + o] = (g != 0.0f) ? sigmoidf_(s) : 0.0f;
}

// ---- o1 ----
__global__ __launch_bounds__(64) void out1k(
        const float* __restrict__ x0, const float* __restrict__ x1,
        const float* __restrict__ w_e1, const float* __restrict__ b_e1,
        const float* __restrict__ w_o1, const float* __restrict__ b_o1,
        const float* __restrict__ w_r1, const float* __restrict__ b_r1,
        const float* __restrict__ ws, float* __restrict__ out) {
    int blk = blockIdx.x; int i = blk % NN, b = blk / NN; int o = threadIdx.x;
    float g  = ws[WS_G + 1];
    float m2 = ws[WS_MF + b * 10 + 2];
    float m3 = ws[WS_MF + b * 10 + 3];
    float m4 = ws[WS_MF + b * 10 + 4];
    float d2 = b_e1[o];
    for (int c = 0; c < NC; ++c) d2 += w_e1[o * NC + c] * x0[b * NC + c];
    float d3 = b_o1[o];
    for (int c = 0; c < NC; ++c) d3 += w_o1[o * NC + c] * x1[(b * NN + i) * NC + c];
    float d4 = b_r1[o];
    for (int c = 0; c < 2 * NC; ++c) d4 += w_r1[o * 2 * NC + c] * ws[WS_R2 + (b * NN + i) * 2 * NC + c];
    float s = m2 * d2 + m3 * d3 + m4 * d4;
    out[(b * NN + i) * NO + o] = (g != 0.0f) ? sigmoidf_(s) : 0.0f;
}

// ---- o2 ----
__global__ __launch_bounds__(64) void out2k(
        const float* __restrict__ x1, const float* __restrict__ x2,
        const float* __restrict__ b_e2, const float* __restrict__ b_o2,
        const float* __restrict__ b_r2,
        const float* __restrict__ ws, float* __restrict__ out) {
    __shared__ float fe[128], fo[128], fr[256];
    int blk = blockIdx.x;
    int j = blk % NN, i = (blk / NN) % NN, b = blk / (NN * NN);
    int o = threadIdx.x;
    float g  = ws[WS_G + 2];
    float m5 = ws[WS_MF + b * 10 + 5];
    float m6 = ws[WS_MF + b * 10 + 6];
    float m7 = ws[WS_MF + b * 10 + 7];
    fe[o]       = x1[(b * NN + i) * NC + o];
    fe[o + 64]  = x1[(b * NN + j) * NC + o];
    fo[o]       = x2[((b * NN + i) * NN + j) * NC + o];
    fo[o + 64]  = x2[((b * NN + j) * NN + i) * NC + o];
    const float* r3ij = ws + WS_R3 + ((b * NN + i) * NN + j) * 128;
    const float* r3ji = ws + WS_R3 + ((b * NN + j) * NN + i) * 128;
    fr[o]        = r3ij[o];
    fr[o + 64]   = r3ij[o + 64];
    fr[o + 128]  = r3ji[o];
    fr[o + 192]  = r3ji[o + 64];
    __syncthreads();
    const float* wte2 = ws + WS_WTE2;
    const float* wto2 = ws + WS_WTO2;
    const float* wtr2 = ws + WS_WTR2;
    float d5 = 0.0f, d6 = 0.0f, d7 = 0.0f;
    #pragma unroll 4
    for (int c = 0; c < 128; ++c) {
        d5 += wte2[c * 64 + o] * fe[c];
        d6 += wto2[c * 64 + o] * fo[c];
    }
    #pragma unroll 4
    for (int c = 0; c < 256; ++c) d7 += wtr2[c * 64 + o] * fr[c];
    float s = m5 * (b_e2[o] + d5) + m6 * (b_o2[o] + d6) + m7 * (b_r2[o] + d7);
    out[((b * NN + i) * NN + j) * NO + o] = (g != 0.0f) ? sigmoidf_(s) : 0.0f;
}

// ---- o3 via MFMA: block per (b,i,j); A[32k][768feat] bf16 in LDS (XOR-swizzled);
// 4 waves = 4 n-tiles of 16 outputs; per wave 2 m-tiles x 24 K-steps of 16x16x32.
// Feature column order: exp3 chunks (i,j),(i,k),(j,i),(k,i),(j,k),(k,j) then
// op3 chunks (i,j,k),(i,k,j),(j,i,k),(k,i,j),(j,k,i),(k,j,i) — masks prescaled in Wc.
__global__ __launch_bounds__(256) void out3k_mfma(
        const float* __restrict__ x2, const float* __restrict__ x3,
        const float* __restrict__ ws_f, float* __restrict__ out) {
    __shared__ unsigned short A[32 * 768];   // 48 KB
    int blk = blockIdx.x;
    int j = blk & 31, i = (blk >> 5) & 31, b = blk >> 10;
    int t = threadIdx.x;
    int lane = t & 63, wv = t >> 6;
    float g3 = ws_f[WS_G + 3];
    const unsigned short* wc = (const unsigned short*)(ws_f + WS_WC);

    // ---- stage A: wave wv handles chunks {wv, wv+4, wv+8} ----
    int ch0 = wv, ch1 = wv + 4, ch2 = wv + 8;
    const float *p0, *p1, *p2; int st0, st1, st2;
    switch (wv) {
      case 0: p0 = x2 + ((b*32+i)*32+j)*64;        st0 = 0;      // c0 (i,j)
              p1 = x2 + ((b*32+j)*32)*64;          st1 = 64;     // c4 (j,k)
              p2 = x3 + (((b*32+j)*32+i)*32)*64;   st2 = 64;     // c8 (j,i,k)
              break;
      case 1: p0 = x2 + ((b*32+i)*32)*64;          st0 = 64;     // c1 (i,k)
              p1 = x2 + (b*1024 + j)*64;           st1 = 2048;   // c5 (k,j)
              p2 = x3 + ((b*1024 + i)*32 + j)*64;  st2 = 65536;  // c9 (k,i,j)
              break;
      case 2: p0 = x2 + ((b*32+j)*32+i)*64;        st0 = 0;      // c2 (j,i)
              p1 = x3 + (((b*32+i)*32+j)*32)*64;   st1 = 64;     // c6 (i,j,k)
              p2 = x3 + (((b*32+j)*32)*32 + i)*64; st2 = 2048;   // c10 (j,k,i)
              break;
      default:p0 = x2 + (b*1024 + i)*64;           st0 = 2048;   // c3 (k,i)
              p1 = x3 + (((b*32+i)*32)*32 + j)*64; st1 = 2048;   // c7 (i,k,j)
              p2 = x3 + (b*32768 + j*32 + i)*64;   st2 = 65536;  // c11 (k,j,i)
              break;
    }
    char* Ab = (char*)A;
    int cb0 = (ch0 * 64 + lane) * 2;
    int cb1 = (ch1 * 64 + lane) * 2;
    int cb2 = (ch2 * 64 + lane) * 2;
    for (int k = 0; k < 32; ++k) {
        float v0 = p0[k * st0 + lane];
        float v1 = p1[k * st1 + lane];
        float v2 = p2[k * st2 + lane];
        int rb = k * 1536, sw = (k & 7) << 4;
        *(unsigned short*)(Ab + ((rb + cb0) ^ sw)) = f2bf(v0);
        *(unsigned short*)(Ab + ((rb + cb1) ^ sw)) = f2bf(v1);
        *(unsigned short*)(Ab + ((rb + cb2) ^ sw)) = f2bf(v2);
    }
    __syncthreads();

    // ---- MFMA main loop ----
    int nt = wv;
    f32x4 acc0 = {0.f, 0.f, 0.f, 0.f};
    f32x4 acc1 = {0.f, 0.f, 0.f, 0.f};
    const unsigned short* wblk = wc + (size_t)((b * 4 + nt) * 24) * 512 + lane * 8;
    int arow0 = lane & 15;
    int arow1 = 16 + arow0;
    int kgrp = (lane >> 4) << 3;
    int sw0 = (arow0 & 7) << 4;           // same for arow1
    #pragma unroll 4
    for (int kk = 0; kk < 24; ++kk) {
        int kloc2 = (kk * 32 + kgrp) * 2;
        bf16x8 a0 = *(const bf16x8*)(Ab + ((arow0 * 1536 + kloc2) ^ sw0));
        bf16x8 a1 = *(const bf16x8*)(Ab + ((arow1 * 1536 + kloc2) ^ sw0));
        bf16x8 bf = *(const bf16x8*)(wblk + kk * 512);
        acc0 = __builtin_amdgcn_mfma_f32_16x16x32_bf16(a0, bf, acc0, 0, 0, 0);
        acc1 = __builtin_amdgcn_mfma_f32_16x16x32_bf16(a1, bf, acc1, 0, 0, 0);
    }

    // ---- epilogue: D col(=o)=lane&15, row(=k)=(lane>>4)*4+reg ----
    int o = nt * 16 + (lane & 15);
    float bias = ws_f[WS_BB + b * 64 + o];
    int rgrp = (lane >> 4) << 2;
    float* obase = out + (size_t)(((b * 32 + i) * 32 + j) * 32) * 64;
    #pragma unroll
    for (int r = 0; r < 4; ++r) {
        float s0 = acc0[r] + bias;
        float s1 = acc1[r] + bias;
        obase[(rgrp + r) * 64 + o]      = (g3 != 0.0f) ? sigmoidf_(s0) : 0.0f;
        obase[(16 + rgrp + r) * 64 + o] = (g3 != 0.0f) ? sigmoidf_(s1) : 0.0f;
    }
}

extern "C" void kernel_launch(void* const* d_in, const int* in_sizes, int n_in,
                              void* d_out, int out_size, void* d_ws, size_t ws_size,
                              hipStream_t stream) {
    const float* x0 = (const float*)d_in[0];
    const float* x1 = (const float*)d_in[1];
    const float* x2 = (const float*)d_in[2];
    const float* x3 = (const float*)d_in[3];
    const float* w_op0 = (const float*)d_in[4];   const float* b_op0 = (const float*)d_in[5];
    const float* w_red0 = (const float*)d_in[6];  const float* b_red0 = (const float*)d_in[7];
    const float* w_exp1 = (const float*)d_in[8];  const float* b_exp1 = (const float*)d_in[9];
    const float* w_op1 = (const float*)d_in[10];  const float* b_op1 = (const float*)d_in[11];
    const float* w_red1 = (const float*)d_in[12]; const float* b_red1 = (const float*)d_in[13];
    const float* w_exp2 = (const float*)d_in[14]; const float* b_exp2 = (const float*)d_in[15];
    const float* w_op2 = (const float*)d_in[16];  const float* b_op2 = (const float*)d_in[17];
    const float* w_red2 = (const float*)d_in[18]; const float* b_red2 = (const float*)d_in[19];
    const float* w_exp3 = (const float*)d_in[20]; const float* b_exp3 = (const float*)d_in[21];
    const float* w_op3 = (const float*)d_in[22];  const float* b_op3 = (const float*)d_in[23];
    const int* act = (const int*)d_in[24];

    float* ws = (float*)d_ws;   // needs ~5.84 MB
    float* out = (float*)d_out;
    float* out0 = out;               // [0, 512)
    float* out1 = out + 512;         // [512, 16896)
    float* out2 = out + 16896;       // [16896, 541184)
    float* out3 = out + 541184;      // [541184, 17318400)

    prep_gm<<<1, 512, 0, stream>>>(act, b_exp3, b_op3, ws);
    prep_wt<<<128, 256, 0, stream>>>(w_exp2, w_op2, w_red2, ws);
    prep_wc<<<1536, 256, 0, stream>>>(w_exp3, w_op3, act, ws);
    red1<<<NB, 64, 0, stream>>>(x1, ws);
    red2<<<NB * NN, 64, 0, stream>>>(x2, ws);
    red3<<<NB * NN * NN, 64, 0, stream>>>(x3, ws);
    out0k<<<NB, 64, 0, stream>>>(x0, w_op0, b_op0, w_red0, b_red0, ws, out0);
    out1k<<<NB * NN, 64, 0, stream>>>(x0, x1, w_exp1, b_exp1, w_op1, b_op1, w_red1, b_red1, ws, out1);
    out2k<<<NB * NN * NN, 64, 0, stream>>>(x1, x2, b_exp2, b_op2, b_red2, ws, out2);
    out3k_mfma<<<NB * NN * NN, 256, 0, stream>>>(x2, x3, ws, out3);
}

// Round 4
// 256.871 us; speedup vs baseline: 5.2399x; 1.2748x over previous
//
#include <hip/hip_runtime.h>
#include <hip/hip_bf16.h>
#include <math.h>

// Shapes (fixed by setup_inputs): B=8, n=32, C=64, O=64
#define NB 8
#define NN 32
#define NC 64
#define NO 64

// ---- workspace layout (float offsets). end = 1,160,192 floats = 4.64 MB ----
#define WS_G    0         // 4: gate for o0..o3
#define WS_MF   16        // 80: act as float
#define WS_R1   128       // 1024 f32: reduce(x1,1) interleaved
#define WS_R2   2048      // 32768 f32: reduce(x2,2) interleaved
#define WS_X1B  36864     // 16384 ushort (8192 slots): x1 as bf16
#define WS_X2B  45056     // 524288 ushort (262144 slots): x2 as bf16
#define WS_R3B  307200    // 1048576 ushort (524288 slots): reduce(x3,3) bf16 interleaved
#define WS_BB   831488    // 512 f32: per-b o3 bias (m8*b_e3 + m9*b_o3)
#define WS_BB2  832000    // 512 f32: per-b o2 bias (m5*b_e2 + m6*b_o2 + m7*b_r2)
#define WS_WC   832512    // 393216 ushort: o3 combined weights, frag-ordered [b][nt][kk24][lane][8]
#define WS_WC2  1029120   // 262144 ushort: o2 combined weights, frag-ordered [b][nt][kk16][lane][8]
// end = 1160192

typedef short bf16x8 __attribute__((ext_vector_type(8)));
typedef unsigned short u16x4 __attribute__((ext_vector_type(4)));
typedef unsigned short u16x8 __attribute__((ext_vector_type(8)));
typedef float f32x4 __attribute__((ext_vector_type(4)));

__device__ __forceinline__ float sigmoidf_(float s) {
    return 1.0f / (1.0f + expf(-s));
}

__device__ __forceinline__ unsigned short f2b(float x) {
    union { __hip_bfloat16 h; unsigned short u; } v;
    v.h = __float2bfloat16(x);   // RNE; compiler pairs into v_cvt_pk_bf16_f32
    return v.u;
}

// ---- prep: gates + per-b float masks + combined biases ----
__global__ void prep_gm(const int* __restrict__ act,
                        const float* __restrict__ be3, const float* __restrict__ bo3,
                        const float* __restrict__ be2, const float* __restrict__ bo2,
                        const float* __restrict__ br2,
                        float* __restrict__ ws) {
    int t = threadIdx.x;
    if (t < 80) ws[WS_MF + t] = (act[t] == 1) ? 1.0f : 0.0f;
    if (t < 4) {
        const int lo[4] = {0, 2, 5, 8};
        const int hi[4] = {2, 5, 8, 10};
        int any = 0;
        for (int b = 0; b < NB; ++b)
            for (int bit = lo[t]; bit < hi[t]; ++bit)
                any |= (act[b * 10 + bit] == 1);
        ws[WS_G + t] = any ? 1.0f : 0.0f;
    }
    if (t < 512) {
        int b = t >> 6, o = t & 63;
        float m8 = (act[b * 10 + 8] == 1) ? 1.0f : 0.0f;
        float m9 = (act[b * 10 + 9] == 1) ? 1.0f : 0.0f;
        ws[WS_BB + t] = m8 * be3[o] + m9 * bo3[o];
        float m5 = (act[b * 10 + 5] == 1) ? 1.0f : 0.0f;
        float m6 = (act[b * 10 + 6] == 1) ? 1.0f : 0.0f;
        float m7 = (act[b * 10 + 7] == 1) ? 1.0f : 0.0f;
        ws[WS_BB2 + t] = m5 * be2[o] + m6 * bo2[o] + m7 * br2[o];
    }
}

// ---- prep: per-b combined o3 weights, bf16, MFMA-fragment-ordered ----
// idx = (((b*4+nt)*24+kk)*64+lane)*8+i8 ; o = nt*16+(lane&15), kloc = kk*32+(lane>>4)*8+i8
// kloc<384 -> m8*w_exp3[o][kloc] ; else m9*w_op3[o][kloc-384]
__global__ void prep_wc(const float* __restrict__ we3, const float* __restrict__ wo3,
                        const int* __restrict__ act, float* __restrict__ ws) {
    int tid = blockIdx.x * 256 + threadIdx.x;   // < 393216
    unsigned short* wc = (unsigned short*)(ws + WS_WC);
    int i8 = tid & 7;
    int lane = (tid >> 3) & 63;
    int rest = tid >> 9;          // 0..767
    int kk = rest % 24;
    int ntb = rest / 24;
    int nt = ntb & 3, b = ntb >> 2;
    int o = nt * 16 + (lane & 15);
    int kloc = kk * 32 + ((lane >> 4) << 3) + i8;
    bool m8 = act[b * 10 + 8] == 1;
    bool m9 = act[b * 10 + 9] == 1;
    float val;
    if (kloc < 384) val = m8 ? we3[o * 384 + kloc] : 0.0f;
    else            val = m9 ? wo3[o * 384 + kloc - 384] : 0.0f;
    wc[tid] = f2b(val);
}

// ---- prep: per-b combined o2 weights, bf16, MFMA-fragment-ordered ----
// K=512: [0,128)=m5*w_exp2, [128,256)=m6*w_op2, [256,512)=m7*w_red2
__global__ void prep_wc2(const float* __restrict__ we2, const float* __restrict__ wo2,
                         const float* __restrict__ wr2, const int* __restrict__ act,
                         float* __restrict__ ws) {
    int tid = blockIdx.x * 256 + threadIdx.x;   // < 262144
    unsigned short* wc2 = (unsigned short*)(ws + WS_WC2);
    int i8 = tid & 7;
    int lane = (tid >> 3) & 63;
    int rest = tid >> 9;          // 0..511 = (b*4+nt)*16+kk
    int kk = rest & 15;
    int ntb = rest >> 4;
    int nt = ntb & 3, b = ntb >> 2;
    int o = nt * 16 + (lane & 15);
    int kloc = kk * 32 + ((lane >> 4) << 3) + i8;
    float val;
    if (kloc < 128)      val = (act[b * 10 + 5] == 1) ? we2[o * 128 + kloc] : 0.0f;
    else if (kloc < 256) val = (act[b * 10 + 6] == 1) ? wo2[o * 128 + kloc - 128] : 0.0f;
    else                 val = (act[b * 10 + 7] == 1) ? wr2[o * 256 + kloc - 256] : 0.0f;
    wc2[tid] = f2b(val);
}

// ---- reduce(x1,1) + x1->bf16 ----
__global__ __launch_bounds__(64) void red1(const float* __restrict__ x1, float* __restrict__ ws) {
    int b = blockIdx.x, c = threadIdx.x;
    unsigned short* x1b = (unsigned short*)(ws + WS_X1B);
    float mx = -INFINITY, mn = INFINITY;
    for (int k = 0; k < NN; ++k) {
        float v = x1[(b * NN + k) * NC + c];
        x1b[(b * NN + k) * NC + c] = f2b(v);
        mx = fmaxf(mx, v); mn = fminf(mn, v);
    }
    ws[WS_R1 + b * 2 * NC + 2 * c]     = mx;
    ws[WS_R1 + b * 2 * NC + 2 * c + 1] = mn;
}

// ---- reduce(x2,2) + x2->bf16 ----
__global__ __launch_bounds__(64) void red2(const float* __restrict__ x2, float* __restrict__ ws) {
    int blk = blockIdx.x; int i = blk % NN, b = blk / NN; int c = threadIdx.x;
    unsigned short* x2b = (unsigned short*)(ws + WS_X2B);
    float mx = -INFINITY, mn = INFINITY;
    for (int jj = 0; jj < NN; ++jj) {
        float v = x2[((b * NN + i) * NN + jj) * NC + c];
        x2b[((b * NN + i) * NN + jj) * NC + c] = f2b(v);
        mx = fmaxf(mx, (jj == i) ? 0.0f : v);
        mn = fminf(mn, (jj == i) ? 1.0f : v);
    }
    ws[WS_R2 + (b * NN + i) * 2 * NC + 2 * c]     = mx;
    ws[WS_R2 + (b * NN + i) * 2 * NC + 2 * c + 1] = mn;
}

// ---- reduce(x3,3) vectorized -> r3b (bf16 interleaved, 128 ushorts per (b,i,j)) ----
__global__ __launch_bounds__(64) void red3(const float* __restrict__ x3, float* __restrict__ ws) {
    int blk = blockIdx.x;
    int j = blk & 31, i = (blk >> 5) & 31, b = blk >> 10;
    int t = threadIdx.x;
    int kg = t >> 4, c4 = (t & 15) << 2;
    const float* base = x3 + (size_t)(((b * 32 + i) * 32 + j) * 32) * 64;
    float mx[4] = {-INFINITY, -INFINITY, -INFINITY, -INFINITY};
    float mn[4] = {INFINITY, INFINITY, INFINITY, INFINITY};
    bool alldiag = (i == j);
    #pragma unroll
    for (int it = 0; it < 8; ++it) {
        int k = it * 4 + kg;
        f32x4 v = *(const f32x4*)(base + k * 64 + c4);
        bool bad = alldiag || (k == i) || (k == j);
        #pragma unroll
        for (int q = 0; q < 4; ++q) {
            mx[q] = fmaxf(mx[q], bad ? 0.0f : v[q]);
            mn[q] = fminf(mn[q], bad ? 1.0f : v[q]);
        }
    }
    #pragma unroll
    for (int off = 16; off < 64; off <<= 1) {
        #pragma unroll
        for (int q = 0; q < 4; ++q) {
            mx[q] = fmaxf(mx[q], __shfl_xor(mx[q], off, 64));
            mn[q] = fminf(mn[q], __shfl_xor(mn[q], off, 64));
        }
    }
    if (t < 16) {
        u16x8 h;
        #pragma unroll
        for (int q = 0; q < 4; ++q) { h[2 * q] = f2b(mx[q]); h[2 * q + 1] = f2b(mn[q]); }
        unsigned short* r3b = (unsigned short*)(ws + WS_R3B);
        // FIX(r3): stride per (b,i,j) slot is 128 ushorts (2C interleaved), was 256 —
        // writer/reader mismatch + 0.5M-float overrun into WS_BB/WS_WC.
        *(u16x8*)(r3b + (size_t)((b * 32 + i) * 32 + j) * 128 + t * 8) = h;
    }
}

// ---- o0 ----
__global__ __launch_bounds__(64) void out0k(
        const float* __restrict__ x0,
        const float* __restrict__ w_op0, const float* __restrict__ b_op0,
        const float* __restrict__ w_red0, const float* __restrict__ b_red0,
        const float* __restrict__ ws, float* __restrict__ out) {
    int b = blockIdx.x, o = threadIdx.x;
    float g  = ws[WS_G + 0];
    float m0 = ws[WS_MF + b * 10 + 0], m1 = ws[WS_MF + b * 10 + 1];
    float d0 = b_op0[o];
    for (int c = 0; c < NC; ++c) d0 += w_op0[o * NC + c] * x0[b * NC + c];
    float d1 = b_red0[o];
    for (int c = 0; c < 2 * NC; ++c) d1 += w_red0[o * 2 * NC + c] * ws[WS_R1 + b * 2 * NC + c];
    float s = m0 * d0 + m1 * d1;
    out[b * NO + o] = (g != 0.0f) ? sigmoidf_(s) : 0.0f;
}

// ---- o1 ----
__global__ __launch_bounds__(64) void out1k(
        const float* __restrict__ x0, const float* __restrict__ x1,
        const float* __restrict__ w_e1, const float* __restrict__ b_e1,
        const float* __restrict__ w_o1, const float* __restrict__ b_o1,
        const float* __restrict__ w_r1, const float* __restrict__ b_r1,
        const float* __restrict__ ws, float* __restrict__ out) {
    int blk = blockIdx.x; int i = blk % NN, b = blk / NN; int o = threadIdx.x;
    float g  = ws[WS_G + 1];
    float m2 = ws[WS_MF + b * 10 + 2];
    float m3 = ws[WS_MF + b * 10 + 3];
    float m4 = ws[WS_MF + b * 10 + 4];
    float d2 = b_e1[o];
    for (int c = 0; c < NC; ++c) d2 += w_e1[o * NC + c] * x0[b * NC + c];
    float d3 = b_o1[o];
    for (int c = 0; c < NC; ++c) d3 += w_o1[o * NC + c] * x1[(b * NN + i) * NC + c];
    float d4 = b_r1[o];
    for (int c = 0; c < 2 * NC; ++c) d4 += w_r1[o * 2 * NC + c] * ws[WS_R2 + (b * NN + i) * 2 * NC + c];
    float s = m2 * d2 + m3 * d3 + m4 * d4;
    out[(b * NN + i) * NO + o] = (g != 0.0f) ? sigmoidf_(s) : 0.0f;
}

// ---- o2 via MFMA: block per (b,i); A[32 j][512 K] bf16 LDS, XOR-swizzled ----
// K layout: [x1b(b,i) | x1b(b,j) | x2b(b,i,j) | x2b(b,j,i) | r3b(b,i,j)(128) | r3b(b,j,i)(128)]
__global__ __launch_bounds__(256) void out2k_mfma(
        const float* __restrict__ ws_f, float* __restrict__ out) {
    __shared__ unsigned short A[32 * 512];   // 32 KB
    int blk = blockIdx.x;
    int i = blk & 31, b = blk >> 5;
    int t = threadIdx.x;
    int lane = t & 63, nt = t >> 6;
    const unsigned short* x1b = (const unsigned short*)(ws_f + WS_X1B);
    const unsigned short* x2b = (const unsigned short*)(ws_f + WS_X2B);
    const unsigned short* r3b = (const unsigned short*)(ws_f + WS_R3B);
    const unsigned short* wc2 = (const unsigned short*)(ws_f + WS_WC2);
    char* Ab = (char*)A;
    // 64-wide chunks c0..c3 (1 pass)
    int r8 = t >> 3, c8 = (t & 7) << 3;
    {
        bf16x8 v0 = *(const bf16x8*)(x1b + (b * 32 + i) * 64 + c8);           // st 0
        bf16x8 v1 = *(const bf16x8*)(x1b + b * 2048 + r8 * 64 + c8);          // j=r8
        bf16x8 v2 = *(const bf16x8*)(x2b + ((b * 32 + i) * 32) * 64 + r8 * 64 + c8);
        bf16x8 v3 = *(const bf16x8*)(x2b + (b * 1024 + i) * 64 + r8 * 2048 + c8);
        int sw = (r8 & 7) << 4;
        *(bf16x8*)(Ab + ((r8 * 1024 + (0 * 64 + c8) * 2) ^ sw)) = v0;
        *(bf16x8*)(Ab + ((r8 * 1024 + (1 * 64 + c8) * 2) ^ sw)) = v1;
        *(bf16x8*)(Ab + ((r8 * 1024 + (2 * 64 + c8) * 2) ^ sw)) = v2;
        *(bf16x8*)(Ab + ((r8 * 1024 + (3 * 64 + c8) * 2) ^ sw)) = v3;
    }
    // 128-wide chunks c4,c5 (2 passes)
    int r16 = t >> 4, c16 = (t & 15) << 3;
    #pragma unroll
    for (int p = 0; p < 2; ++p) {
        int jr = p * 16 + r16;
        bf16x8 v4 = *(const bf16x8*)(r3b + ((b * 32 + i) * 32 + jr) * 128 + c16);
        bf16x8 v5 = *(const bf16x8*)(r3b + ((b * 32 + jr) * 32 + i) * 128 + c16);
        int sw = (jr & 7) << 4;
        *(bf16x8*)(Ab + ((jr * 1024 + (256 + c16) * 2) ^ sw)) = v4;
        *(bf16x8*)(Ab + ((jr * 1024 + (384 + c16) * 2) ^ sw)) = v5;
    }
    __syncthreads();
    f32x4 acc0 = {0.f, 0.f, 0.f, 0.f};
    f32x4 acc1 = {0.f, 0.f, 0.f, 0.f};
    const unsigned short* wblk = wc2 + (size_t)((b * 4 + nt) * 16) * 512 + lane * 8;
    int arow0 = lane & 15, arow1 = 16 + arow0;
    int kgrp = (lane >> 4) << 3;
    int sw0 = (arow0 & 7) << 4;
    #pragma unroll
    for (int kk = 0; kk < 16; ++kk) {
        int kloc2 = (kk * 32 + kgrp) * 2;
        bf16x8 a0 = *(const bf16x8*)(Ab + ((arow0 * 1024 + kloc2) ^ sw0));
        bf16x8 a1 = *(const bf16x8*)(Ab + ((arow1 * 1024 + kloc2) ^ sw0));
        bf16x8 bf = *(const bf16x8*)(wblk + kk * 512);
        acc0 = __builtin_amdgcn_mfma_f32_16x16x32_bf16(a0, bf, acc0, 0, 0, 0);
        acc1 = __builtin_amdgcn_mfma_f32_16x16x32_bf16(a1, bf, acc1, 0, 0, 0);
    }
    float g2 = ws_f[WS_G + 2];
    int o = nt * 16 + (lane & 15);
    float bias = ws_f[WS_BB2 + b * 64 + o];
    int rgrp = (lane >> 4) << 2;
    float* obase = out + (size_t)((b * 32 + i) * 32) * 64;
    #pragma unroll
    for (int r = 0; r < 4; ++r) {
        float s0 = acc0[r] + bias;
        float s1 = acc1[r] + bias;
        obase[(rgrp + r) * 64 + o]      = (g2 != 0.0f) ? sigmoidf_(s0) : 0.0f;
        obase[(16 + rgrp + r) * 64 + o] = (g2 != 0.0f) ? sigmoidf_(s1) : 0.0f;
    }
}

// ---- o3 via MFMA: block per (b,i,j); A[32 k][768 K] bf16 LDS, XOR-swizzled ----
// K layout: exp3 x2-chunks (i,j),(i,k),(j,i),(k,i),(j,k),(k,j) then
//           op3  x3-chunks (i,j,k),(i,k,j),(j,i,k),(k,i,j),(j,k,i),(k,j,i)
__global__ __launch_bounds__(256) void out3k_mfma(
        const float* __restrict__ x3, const float* __restrict__ ws_f,
        float* __restrict__ out) {
    __shared__ unsigned short A[32 * 768];   // 48 KB
    int blk = blockIdx.x;
    int j = blk & 31, i = (blk >> 5) & 31, b = blk >> 10;
    int t = threadIdx.x;
    int lane = t & 63, wv = t >> 6;
    const unsigned short* x2b = (const unsigned short*)(ws_f + WS_X2B);
    const unsigned short* wc = (const unsigned short*)(ws_f + WS_WC);
    char* Ab = (char*)A;

    // x2b chunks (bf16, 1 pass each): row k = t>>3, col = (t&7)*8
    {
        int r8 = t >> 3, c8 = (t & 7) << 3;
        size_t cb[6]; int cs[6];
        cb[0] = ((b * 32 + i) * 32 + j) * 64; cs[0] = 0;
        cb[1] = ((b * 32 + i) * 32) * 64;     cs[1] = 64;
        cb[2] = ((b * 32 + j) * 32 + i) * 64; cs[2] = 0;
        cb[3] = (b * 1024 + i) * 64;          cs[3] = 2048;
        cb[4] = ((b * 32 + j) * 32) * 64;     cs[4] = 64;
        cb[5] = (b * 1024 + j) * 64;          cs[5] = 2048;
        int sw = (r8 & 7) << 4;
        #pragma unroll
        for (int ch = 0; ch < 6; ++ch) {
            bf16x8 v = *(const bf16x8*)(x2b + cb[ch] + (size_t)r8 * cs[ch] + c8);
            *(bf16x8*)(Ab + ((r8 * 1536 + (ch * 64 + c8) * 2) ^ sw)) = v;
        }
    }
    // x3 chunks (f32 -> bf16, 2 passes each): row k = p*16 + (t>>4), col = (t&15)*4
    {
        int r16 = t >> 4, c4 = (t & 15) << 2;
        const float* xb[6]; int xs[6];
        xb[0] = x3 + (size_t)(((b * 32 + i) * 32 + j) * 32) * 64; xs[0] = 64;
        xb[1] = x3 + (size_t)(((b * 32 + i) * 32) * 32 + j) * 64; xs[1] = 2048;
        xb[2] = x3 + (size_t)(((b * 32 + j) * 32 + i) * 32) * 64; xs[2] = 64;
        xb[3] = x3 + (size_t)((b * 1024 + i) * 32 + j) * 64;      xs[3] = 65536;
        xb[4] = x3 + (size_t)(((b * 32 + j) * 32) * 32 + i) * 64; xs[4] = 2048;
        xb[5] = x3 + (size_t)(b * 32768 + j * 32 + i) * 64;       xs[5] = 65536;
        #pragma unroll
        for (int ch = 0; ch < 6; ++ch) {
            #pragma unroll
            for (int p = 0; p < 2; ++p) {
                int k = p * 16 + r16;
                f32x4 v = *(const f32x4*)(xb[ch] + (size_t)k * xs[ch] + c4);
                u16x4 h = { f2b(v[0]), f2b(v[1]), f2b(v[2]), f2b(v[3]) };
                *(u16x4*)(Ab + ((k * 1536 + ((6 + ch) * 64 + c4) * 2) ^ ((k & 7) << 4))) = h;
            }
        }
    }
    __syncthreads();

    // MFMA main loop: wave = n-tile, 2 m-tiles x 24 K-steps
    int nt = wv;
    f32x4 acc0 = {0.f, 0.f, 0.f, 0.f};
    f32x4 acc1 = {0.f, 0.f, 0.f, 0.f};
    const unsigned short* wblk = wc + (size_t)((b * 4 + nt) * 24) * 512 + lane * 8;
    int arow0 = lane & 15;
    int arow1 = 16 + arow0;
    int kgrp = (lane >> 4) << 3;
    int sw0 = (arow0 & 7) << 4;
    #pragma unroll 4
    for (int kk = 0; kk < 24; ++kk) {
        int kloc2 = (kk * 32 + kgrp) * 2;
        bf16x8 a0 = *(const bf16x8*)(Ab + ((arow0 * 1536 + kloc2) ^ sw0));
        bf16x8 a1 = *(const bf16x8*)(Ab + ((arow1 * 1536 + kloc2) ^ sw0));
        bf16x8 bf = *(const bf16x8*)(wblk + kk * 512);
        acc0 = __builtin_amdgcn_mfma_f32_16x16x32_bf16(a0, bf, acc0, 0, 0, 0);
        acc1 = __builtin_amdgcn_mfma_f32_16x16x32_bf16(a1, bf, acc1, 0, 0, 0);
    }

    // epilogue: D col(=o)=lane&15, row(=k)=(lane>>4)*4+reg
    float g3 = ws_f[WS_G + 3];
    int o = nt * 16 + (lane & 15);
    float bias = ws_f[WS_BB + b * 64 + o];
    int rgrp = (lane >> 4) << 2;
    float* obase = out + (size_t)(((b * 32 + i) * 32 + j) * 32) * 64;
    #pragma unroll
    for (int r = 0; r < 4; ++r) {
        float s0 = acc0[r] + bias;
        float s1 = acc1[r] + bias;
        obase[(rgrp + r) * 64 + o]      = (g3 != 0.0f) ? sigmoidf_(s0) : 0.0f;
        obase[(16 + rgrp + r) * 64 + o] = (g3 != 0.0f) ? sigmoidf_(s1) : 0.0f;
    }
}

extern "C" void kernel_launch(void* const* d_in, const int* in_sizes, int n_in,
                              void* d_out, int out_size, void* d_ws, size_t ws_size,
                              hipStream_t stream) {
    const float* x0 = (const float*)d_in[0];
    const float* x1 = (const float*)d_in[1];
    const float* x2 = (const float*)d_in[2];
    const float* x3 = (const float*)d_in[3];
    const float* w_op0 = (const float*)d_in[4];   const float* b_op0 = (const float*)d_in[5];
    const float* w_red0 = (const float*)d_in[6];  const float* b_red0 = (const float*)d_in[7];
    const float* w_exp1 = (const float*)d_in[8];  const float* b_exp1 = (const float*)d_in[9];
    const float* w_op1 = (const float*)d_in[10];  const float* b_op1 = (const float*)d_in[11];
    const float* w_red1 = (const float*)d_in[12]; const float* b_red1 = (const float*)d_in[13];
    const float* w_exp2 = (const float*)d_in[14]; const float* b_exp2 = (const float*)d_in[15];
    const float* w_op2 = (const float*)d_in[16];  const float* b_op2 = (const float*)d_in[17];
    const float* w_red2 = (const float*)d_in[18]; const float* b_red2 = (const float*)d_in[19];
    const float* w_exp3 = (const float*)d_in[20]; const float* b_exp3 = (const float*)d_in[21];
    const float* w_op3 = (const float*)d_in[22];  const float* b_op3 = (const float*)d_in[23];
    const int* act = (const int*)d_in[24];

    float* ws = (float*)d_ws;   // needs ~4.64 MB
    float* out = (float*)d_out;
    float* out0 = out;               // [0, 512)
    float* out1 = out + 512;         // [512, 16896)
    float* out2 = out + 16896;       // [16896, 541184)
    float* out3 = out + 541184;      // [541184, 17318400)

    prep_gm<<<1, 512, 0, stream>>>(act, b_exp3, b_op3, b_exp2, b_op2, b_red2, ws);
    prep_wc<<<1536, 256, 0, stream>>>(w_exp3, w_op3, act, ws);
    prep_wc2<<<1024, 256, 0, stream>>>(w_exp2, w_op2, w_red2, act, ws);
    red1<<<NB, 64, 0, stream>>>(x1, ws);
    red2<<<NB * NN, 64, 0, stream>>>(x2, ws);
    red3<<<NB * NN * NN, 64, 0, stream>>>(x3, ws);
    out0k<<<NB, 64, 0, stream>>>(x0, w_op0, b_op0, w_red0, b_red0, ws, out0);
    out1k<<<NB * NN, 64, 0, stream>>>(x0, x1, w_exp1, b_exp1, w_op1, b_op1, w_red1, b_red1, ws, out1);
    out2k_mfma<<<NB * NN, 256, 0, stream>>>(ws, out2);
    out3k_mfma<<<NB * NN * NN, 256, 0, stream>>>(x3, ws, out3);
}